// Round 7
// baseline (111.051 us; speedup 1.0000x reference)
//
#include <hip/hip_runtime.h>
#include <stdint.h>

#define HEADS 4
#define NEG_SLOPE 0.2f
#define MB 64      // rows per block in projection kernel

typedef _Float16 f16;
typedef f16 f16x8 __attribute__((ext_vector_type(8)));
typedef f16 f16x4 __attribute__((ext_vector_type(4)));
typedef f16 f16x2 __attribute__((ext_vector_type(2)));
typedef float f32x4 __attribute__((ext_vector_type(4)));
typedef unsigned int u32x4 __attribute__((ext_vector_type(4)));

// swizzled LDS byte offset for a [rows][128] f16 tile (256 B rows):
// XOR row bits into the 16B-slot bits to kill the 16-way bank conflict
#define SWZ(row, kb) (((row) << 8) + ((kb) ^ (((row) & 7) << 4)))

// ---- pre-kernel: w (f32 [K=128][N=128]) -> wt (f16 [N=128][K=128]) ----
__global__ __launch_bounds__(256) void wt_kernel(const float* __restrict__ w,
                                                 f16* __restrict__ wt) {
    __shared__ f16 tl[16][136];  // +8 pad
    const int b = blockIdx.x, t = threadIdx.x;
    for (int i = t; i < 2048; i += 256) {   // 128 k-rows x 16 cols of this slice
        int k = i >> 4, nl = i & 15;
        tl[nl][k] = (f16)w[k * 128 + b * 16 + nl];
    }
    __syncthreads();
    {
        int nl = t >> 4, kc = t & 15;       // 16 rows x 16 chunks = 256 threads
        f16x8 v = *(const f16x8*)&tl[nl][kc * 8];
        *(f16x8*)(wt + (b * 16 + nl) * 128 + kc * 8) = v;
    }
}

// ---- projection: xp = f16(x) @ f16(w) via MFMA + a_src/a_dst logit dots ----
// xp is written in SLICED layout: [8 slices of 16 cols][node][16] f16, so the
// aggregation pass on XCD s only touches slice s (3.2 MB, fits 4 MB L2).
__global__ __launch_bounds__(256) void gat_proj_mfma(
    const float* __restrict__ x, const f16* __restrict__ wt,
    const float* __restrict__ att, f16* __restrict__ xp,
    float* __restrict__ a_src, float* __restrict__ a_dst, int n) {
    __shared__ unsigned char lds[32768];
    __shared__ float att_l[256];
    const int t = threadIdx.x;
    const int node0 = blockIdx.x * MB;
    const int lane = t & 63;
    const int wv = t >> 6;

    att_l[t] = att[t];

    // A-frags: row = node0 + wv*16 + (lane&15); kt-frag cols kt*32+(lane>>4)*8..+8
    const int arow = node0 + wv * 16 + (lane & 15);
    const bool rowok = arow < n;
    const float* xr = x + (size_t)arow * 128 + (lane >> 4) * 8;
    f16x8 afr[4];
#pragma unroll
    for (int kt = 0; kt < 4; kt++) {
        float4 a = make_float4(0.f, 0.f, 0.f, 0.f), b = a;
        if (rowok) {
            a = *(const float4*)(xr + kt * 32);
            b = *(const float4*)(xr + kt * 32 + 4);
        }
        f16x8 hv;
        hv[0] = (f16)a.x; hv[1] = (f16)a.y; hv[2] = (f16)a.z; hv[3] = (f16)a.w;
        hv[4] = (f16)b.x; hv[5] = (f16)b.y; hv[6] = (f16)b.z; hv[7] = (f16)b.w;
        afr[kt] = hv;
    }

    // stage wt (f16, [N][K]) into swizzled LDS
    for (int i = t; i < 2048; i += 256) {
        int row = i >> 4, kc = i & 15;
        uint4 v = *(const uint4*)(wt + row * 128 + kc * 8);
        *(uint4*)(lds + SWZ(row, kc * 16)) = v;
    }
    __syncthreads();

    // MFMA: wave wv owns rows wv*16..+15 (1 M-frag), all 128 cols
    f32x4 acc[8];
#pragma unroll
    for (int nf = 0; nf < 8; nf++) acc[nf] = (f32x4){0.f, 0.f, 0.f, 0.f};

#pragma unroll
    for (int kt = 0; kt < 4; kt++) {
        const int kb = kt * 64 + (lane >> 4) * 16;
#pragma unroll
        for (int nf = 0; nf < 8; nf++) {
            f16x8 bfr = *(const f16x8*)(lds + SWZ(nf * 16 + (lane & 15), kb));
            acc[nf] = __builtin_amdgcn_mfma_f32_16x16x32_f16(afr[kt], bfr, acc[nf], 0, 0, 0);
        }
    }

    // repack accumulators (f16) into the (now-free) wt LDS region
    __syncthreads();  // all wt reads done
#pragma unroll
    for (int r = 0; r < 4; r++) {
        int row = wv * 16 + (lane >> 4) * 4 + r;
#pragma unroll
        for (int nf = 0; nf < 8; nf++) {
            int col = nf * 16 + (lane & 15);
            *(f16*)(lds + SWZ(row, col * 2)) = (f16)acc[nf][r];
        }
    }
    __syncthreads();

    // a_src[n,h] = sum_c xp[n,h*32+c]*att[h*32+c]; a_dst with att[128+..]
    {
        int row = t >> 2, h = t & 3;        // 64 rows x 4 heads = 256 threads
        int grow = node0 + row;
        if (grow < n) {
            float s = 0.f, d = 0.f;
#pragma unroll
            for (int cc = 0; cc < 4; cc++) {
                f16x8 v = *(const f16x8*)(lds + SWZ(row, h * 64 + cc * 16));
#pragma unroll
                for (int j = 0; j < 8; j++) {
                    float xv = (float)v[j];
                    int c = cc * 8 + j;
                    s = fmaf(xv, att_l[h * 32 + c], s);
                    d = fmaf(xv, att_l[128 + h * 32 + c], d);
                }
            }
            a_src[(size_t)grow * HEADS + h] = s;
            a_dst[(size_t)grow * HEADS + h] = d;
        }
    }
    // write xp tile out in SLICED layout (16B stores, NORMAL caching: the
    // aggregation pass relies on L2/L3 residency of these lines)
    for (int i = t; i < 1024; i += 256) {
        int row = i >> 4, kc = i & 15;
        int grow = node0 + row;
        if (grow < n) {
            u32x4 v = *(const u32x4*)(lds + SWZ(row, kc * 16));
            int slice = kc >> 1;
            *(u32x4*)(xp + ((size_t)slice * n + grow) * 16 + (kc & 1) * 8) = v;
        }
    }
}

// ---- alpha kernel: per-edge softmax weights into per-head planes ----
// alpha[h][node*8+e] (f16), 0 for invalid edge slots. 4 nodes per wave.
__global__ __launch_bounds__(256) void gat_alpha_kernel(
    const float* __restrict__ a_src, const float* __restrict__ a_dst,
    const int* __restrict__ row_ptr, const int* __restrict__ col_ind,
    f16* __restrict__ alpha, int n, int e_total) {
    const int lane = threadIdx.x & 63;
    const int p = lane >> 5, l = lane & 31;
    const int nb = (blockIdx.x * 4 + (threadIdx.x >> 6)) * 4;
    if (nb >= n) return;

    int rp = 0;
    if (lane < 5) {
        int idx = nb + lane;
        if (idx > n) idx = n;
        rp = row_ptr[idx];
    }
    int ci = 0;
    {
        int si = nb * 8 + lane;
        if (lane < 32 && si < e_total) ci = col_ind[si];
    }

    int rs0 = __shfl(rp, 0, 64), rs1 = __shfl(rp, 1, 64), rs2 = __shfl(rp, 2, 64);
    int rs3 = __shfl(rp, 3, 64), rs4 = __shfl(rp, 4, 64);
    int dg0 = rs1 - rs0, dg1 = rs2 - rs1, dg2 = rs3 - rs2, dg3 = rs4 - rs3;
    if (dg0 > 8) dg0 = 8;
    if (dg1 > 8) dg1 = 8;
    if (dg2 > 8) dg2 = 8;
    if (dg3 > 8) dg3 = 8;
    if (nb + 1 >= n) dg1 = 0;
    if (nb + 2 >= n) dg2 = 0;
    if (nb + 3 >= n) dg3 = 0;
    bool ok = (nb + 4 <= n) && (rs0 == nb * 8) && (rs1 == rs0 + 8) &&
              (rs2 == rs1 + 8) && (rs3 == rs2 + 8) && (rs4 == rs3 + 8);
    if (!ok) {  // cold path (never taken for this graph)
        int j = lane >> 3, e = lane & 7;
        int rsj = (j == 0) ? rs0 : (j == 1) ? rs1 : (j == 2) ? rs2 : rs3;
        int dgj = (j == 0) ? dg0 : (j == 1) ? dg1 : (j == 2) ? dg2 : dg3;
        int v = 0;
        if (lane < 32 && e < dgj) v = col_ind[rsj + e];
        ci = v;
    }

    const int ea = (l >> 2) & 7, ha = l & 3;
    const int dsel0 = p ? dg1 : dg0;
    const int dsel1 = p ? dg3 : dg2;
    int sa0 = __shfl(ci, (0 * 2 + p) * 8 + ea, 64);
    int sa1 = __shfl(ci, (1 * 2 + p) * 8 + ea, 64);
    float av0 = (ea < dsel0) ? a_src[(size_t)sa0 * HEADS + ha] : 0.f;
    float av1 = (ea < dsel1) ? a_src[(size_t)sa1 * HEADS + ha] : 0.f;
    float dv0 = (nb + p < n) ? a_dst[(size_t)(nb + p) * HEADS + ha] : 0.f;
    float dv1 = (nb + 2 + p < n) ? a_dst[(size_t)(nb + 2 + p) * HEADS + ha] : 0.f;

#pragma unroll
    for (int q = 0; q < 2; q++) {
        const int node = nb + 2 * q + p;
        const int dsel = q ? dsel1 : dsel0;
        float z = (q ? av1 : av0) + (q ? dv1 : dv0);
        float v = (ea < dsel) ? ((z >= 0.f) ? z : NEG_SLOPE * z) : -1e30f;
        float m = v;
        m = fmaxf(m, __shfl_xor(m, 4, 64));
        m = fmaxf(m, __shfl_xor(m, 8, 64));
        m = fmaxf(m, __shfl_xor(m, 16, 64));
        float ex = (ea < dsel) ? __expf(v - m) : 0.f;
        float ss = ex;
        ss += __shfl_xor(ss, 4, 64);
        ss += __shfl_xor(ss, 8, 64);
        ss += __shfl_xor(ss, 16, 64);
        float al = ex * ((ss > 0.f) ? (1.f / ss) : 0.f);
        if (node < n)
            alpha[(size_t)ha * n * 8 + (size_t)node * 8 + ea] = (f16)al;
    }
}

// ---- sliced aggregation: block (bid%8)==s handles 16-col slice s ----
// XCD round-robin dispatch puts all slice-s blocks on XCD s, whose 4 MB L2
// holds the whole 3.2 MB slice -> gathers are L2 hits after cold fill.
// One wave = 8 nodes; per node ONE f16x2 gather instr (lane: e=lane>>3 edge,
// c2=lane&7 col-pair), reduce over e via xor 8/16/32.
__global__ __launch_bounds__(256) void gat_slice_aggr(
    const f16* __restrict__ xp, const f16* __restrict__ alpha,
    const int* __restrict__ row_ptr, const int* __restrict__ col_ind,
    const float* __restrict__ bias, float* __restrict__ out, int n, int e_total) {
    const int slice = blockIdx.x & 7;
    const int chunk = blockIdx.x >> 3;
    const int lane = threadIdx.x & 63;
    const int nb = chunk * 32 + (threadIdx.x >> 6) * 8;
    if (nb >= n) return;

    const f16* xps = xp + (size_t)slice * n * 16;
    const f16* alp = alpha + (size_t)(slice >> 1) * n * 8;

    int rp = 0;
    if (lane < 9) {
        int idx = nb + lane;
        if (idx > n) idx = n;
        rp = row_ptr[idx];
    }
    int ci = 0;
    {
        long long si = (long long)nb * 8 + lane;
        if (si < e_total) ci = col_ind[si];
    }
    int avi = 0;
    {
        long long ai = (long long)nb * 8 + lane;
        if (ai < (long long)n * 8) avi = *(const unsigned short*)(alp + ai);
    }
    const int e = lane >> 3, c2 = lane & 7;
    float2 b2 = *(const float2*)(bias + slice * 16 + c2 * 2);

    bool ok = __all((lane < 9) ? (rp == (nb + lane) * 8) : 1) && (nb + 8 <= n);

    float sto0 = 0.f, sto1 = 0.f;
#pragma unroll
    for (int nd = 0; nd < 8; nd++) {
        int src, abits;
        if (ok) {
            src = __shfl(ci, nd * 8 + e, 64);
            abits = __shfl(avi, nd * 8 + e, 64);
        } else {  // cold path (never taken for this graph)
            int rs = __shfl(rp, nd, 64), re = __shfl(rp, nd + 1, 64);
            int dg = re - rs;
            if (dg > 8) dg = 8;
            if (nb + nd >= n) dg = 0;
            src = (e < dg) ? col_ind[rs + e] : 0;
            abits = (nb + nd < n) ? *(const unsigned short*)(alp + (size_t)(nb + nd) * 8 + e) : 0;
        }
        unsigned short ab16 = (unsigned short)abits;
        float a = (float)(*(const f16*)&ab16);
        f16x2 v = *(const f16x2*)(xps + (size_t)src * 16 + c2 * 2);
        float p0 = a * (float)v[0];
        float p1 = a * (float)v[1];
        p0 += __shfl_xor(p0, 8, 64);
        p1 += __shfl_xor(p1, 8, 64);
        p0 += __shfl_xor(p0, 16, 64);
        p1 += __shfl_xor(p1, 16, 64);
        p0 += __shfl_xor(p0, 32, 64);
        p1 += __shfl_xor(p1, 32, 64);
        // store-lane mapping: lane group e stores node nb+e
        sto0 = (nd == e) ? p0 : sto0;
        sto1 = (nd == e) ? p1 : sto1;
    }
    const int snode = nb + e;
    if (snode < n) {
        float2 o = make_float2(sto0 + b2.x, sto1 + b2.y);
        __builtin_nontemporal_store(o.x, out + (size_t)snode * 128 + slice * 16 + c2 * 2);
        __builtin_nontemporal_store(o.y, out + (size_t)snode * 128 + slice * 16 + c2 * 2 + 1);
    }
}

extern "C" void kernel_launch(void* const* d_in, const int* in_sizes, int n_in,
                              void* d_out, int out_size, void* d_ws, size_t ws_size,
                              hipStream_t stream) {
    const float* x = (const float*)d_in[0];
    const int* row_ptr = (const int*)d_in[1];
    const int* col_ind = (const int*)d_in[2];
    // d_in[3] = max_num_neighbors (row_ptr is authoritative)
    const float* lin_w = (const float*)d_in[4];
    const float* att = (const float*)d_in[5];
    const float* bias = (const float*)d_in[6];
    float* out = (float*)d_out;
    const int n = in_sizes[0] / 128;
    const int e_total = in_sizes[2];

    // ws layout
    f16* xp = (f16*)d_ws;                                   // [8][n][16] f16 = n*256 B
    float* a_src = (float*)((char*)d_ws + (size_t)n * 256); // n*4 f32
    float* a_dst = a_src + (size_t)n * HEADS;               // n*4 f32
    f16* alpha = (f16*)(a_dst + (size_t)n * HEADS);         // [4][n*8] f16
    f16* wt = alpha + (size_t)n * 32 + 128;                 // 128*128 f16 (+pad)

    hipLaunchKernelGGL(wt_kernel, dim3(8), dim3(256), 0, stream, lin_w, wt);
    hipLaunchKernelGGL(gat_proj_mfma, dim3((n + MB - 1) / MB), dim3(256), 0, stream,
                       x, wt, att, xp, a_src, a_dst, n);
    hipLaunchKernelGGL(gat_alpha_kernel, dim3((n + 15) / 16), dim3(256), 0, stream,
                       a_src, a_dst, row_ptr, col_ind, alpha, n, e_total);
    hipLaunchKernelGGL(gat_slice_aggr, dim3(8 * ((n + 31) / 32)), dim3(256), 0, stream,
                       xp, alpha, row_ptr, col_ind, bias, out, n, e_total);
}

// Round 8
// 77.819 us; speedup vs baseline: 1.4270x; 1.4270x over previous
//
#include <hip/hip_runtime.h>
#include <stdint.h>

#define HEADS 4
#define NEG_SLOPE 0.2f
#define MB 64      // rows per block in projection kernel

typedef _Float16 f16;
typedef f16 f16x8 __attribute__((ext_vector_type(8)));
typedef f16 f16x4 __attribute__((ext_vector_type(4)));
typedef float f32x4 __attribute__((ext_vector_type(4)));
typedef unsigned int u32x4 __attribute__((ext_vector_type(4)));

// swizzled LDS byte offset for a [rows][128] f16 tile (256 B rows):
// XOR row bits into the 16B-slot bits to kill the 16-way bank conflict
#define SWZ(row, kb) (((row) << 8) + ((kb) ^ (((row) & 7) << 4)))

// ---- pre-kernel: w (f32 [K=128][N=128]) -> wt (f16 [N=128][K=128]) ----
__global__ __launch_bounds__(256) void wt_kernel(const float* __restrict__ w,
                                                 f16* __restrict__ wt) {
    __shared__ f16 tl[16][136];  // +8 pad
    const int b = blockIdx.x, t = threadIdx.x;
    for (int i = t; i < 2048; i += 256) {   // 128 k-rows x 16 cols of this slice
        int k = i >> 4, nl = i & 15;
        tl[nl][k] = (f16)w[k * 128 + b * 16 + nl];
    }
    __syncthreads();
    {
        int nl = t >> 4, kc = t & 15;       // 16 rows x 16 chunks = 256 threads
        f16x8 v = *(const f16x8*)&tl[nl][kc * 8];
        *(f16x8*)(wt + (b * 16 + nl) * 128 + kc * 8) = v;
    }
}

// ---- projection: xp = f16(x) @ f16(w) via MFMA + a_src/a_dst logit dots ----
// xp is written in SLICED layout: [8 slices of 16 cols][node][16] f16, so the
// aggregation pass on XCD s only touches slice s (3.2 MB, fits 4 MB L2).
__global__ __launch_bounds__(256) void gat_proj_mfma(
    const float* __restrict__ x, const f16* __restrict__ wt,
    const float* __restrict__ att, f16* __restrict__ xp,
    float* __restrict__ a_src, float* __restrict__ a_dst, int n) {
    __shared__ unsigned char lds[32768];
    __shared__ float att_l[256];
    const int t = threadIdx.x;
    const int node0 = blockIdx.x * MB;
    const int lane = t & 63;
    const int wv = t >> 6;

    att_l[t] = att[t];

    // A-frags: row = node0 + wv*16 + (lane&15); kt-frag cols kt*32+(lane>>4)*8..+8
    const int arow = node0 + wv * 16 + (lane & 15);
    const bool rowok = arow < n;
    const float* xr = x + (size_t)arow * 128 + (lane >> 4) * 8;
    f16x8 afr[4];
#pragma unroll
    for (int kt = 0; kt < 4; kt++) {
        float4 a = make_float4(0.f, 0.f, 0.f, 0.f), b = a;
        if (rowok) {
            a = *(const float4*)(xr + kt * 32);
            b = *(const float4*)(xr + kt * 32 + 4);
        }
        f16x8 hv;
        hv[0] = (f16)a.x; hv[1] = (f16)a.y; hv[2] = (f16)a.z; hv[3] = (f16)a.w;
        hv[4] = (f16)b.x; hv[5] = (f16)b.y; hv[6] = (f16)b.z; hv[7] = (f16)b.w;
        afr[kt] = hv;
    }

    // stage wt (f16, [N][K]) into swizzled LDS
    for (int i = t; i < 2048; i += 256) {
        int row = i >> 4, kc = i & 15;
        uint4 v = *(const uint4*)(wt + row * 128 + kc * 8);
        *(uint4*)(lds + SWZ(row, kc * 16)) = v;
    }
    __syncthreads();

    // MFMA: wave wv owns rows wv*16..+15 (1 M-frag), all 128 cols
    f32x4 acc[8];
#pragma unroll
    for (int nf = 0; nf < 8; nf++) acc[nf] = (f32x4){0.f, 0.f, 0.f, 0.f};

#pragma unroll
    for (int kt = 0; kt < 4; kt++) {
        const int kb = kt * 64 + (lane >> 4) * 16;
#pragma unroll
        for (int nf = 0; nf < 8; nf++) {
            f16x8 bfr = *(const f16x8*)(lds + SWZ(nf * 16 + (lane & 15), kb));
            acc[nf] = __builtin_amdgcn_mfma_f32_16x16x32_f16(afr[kt], bfr, acc[nf], 0, 0, 0);
        }
    }

    // repack accumulators (f16) into the (now-free) wt LDS region
    __syncthreads();  // all wt reads done
#pragma unroll
    for (int r = 0; r < 4; r++) {
        int row = wv * 16 + (lane >> 4) * 4 + r;
#pragma unroll
        for (int nf = 0; nf < 8; nf++) {
            int col = nf * 16 + (lane & 15);
            *(f16*)(lds + SWZ(row, col * 2)) = (f16)acc[nf][r];
        }
    }
    __syncthreads();

    // a_src[n,h] = sum_c xp[n,h*32+c]*att[h*32+c]; a_dst with att[128+..]
    {
        int row = t >> 2, h = t & 3;        // 64 rows x 4 heads = 256 threads
        int grow = node0 + row;
        if (grow < n) {
            float s = 0.f, d = 0.f;
#pragma unroll
            for (int cc = 0; cc < 4; cc++) {
                f16x8 v = *(const f16x8*)(lds + SWZ(row, h * 64 + cc * 16));
#pragma unroll
                for (int j = 0; j < 8; j++) {
                    float xv = (float)v[j];
                    int c = cc * 8 + j;
                    s = fmaf(xv, att_l[h * 32 + c], s);
                    d = fmaf(xv, att_l[128 + h * 32 + c], d);
                }
            }
            a_src[(size_t)grow * HEADS + h] = s;
            a_dst[(size_t)grow * HEADS + h] = d;
        }
    }
    // write xp tile out in SLICED layout (16B stores, NORMAL caching: the
    // aggregation pass relies on L2 residency of these lines)
    for (int i = t; i < 1024; i += 256) {
        int row = i >> 4, kc = i & 15;
        int grow = node0 + row;
        if (grow < n) {
            u32x4 v = *(const u32x4*)(lds + SWZ(row, kc * 16));
            int slice = kc >> 1;
            *(u32x4*)(xp + ((size_t)slice * n + grow) * 16 + (kc & 1) * 8) = v;
        }
    }
}

// ---- alpha kernel: per-edge softmax weights into per-head planes ----
// alpha[h][node*8+e] (f16), 0 for invalid edge slots. 4 nodes per wave.
__global__ __launch_bounds__(256) void gat_alpha_kernel(
    const float* __restrict__ a_src, const float* __restrict__ a_dst,
    const int* __restrict__ row_ptr, const int* __restrict__ col_ind,
    f16* __restrict__ alpha, int n, int e_total) {
    const int lane = threadIdx.x & 63;
    const int p = lane >> 5, l = lane & 31;
    const int nb = (blockIdx.x * 4 + (threadIdx.x >> 6)) * 4;
    if (nb >= n) return;

    int rp = 0;
    if (lane < 5) {
        int idx = nb + lane;
        if (idx > n) idx = n;
        rp = row_ptr[idx];
    }
    int ci = 0;
    {
        int si = nb * 8 + lane;
        if (lane < 32 && si < e_total) ci = col_ind[si];
    }

    int rs0 = __shfl(rp, 0, 64), rs1 = __shfl(rp, 1, 64), rs2 = __shfl(rp, 2, 64);
    int rs3 = __shfl(rp, 3, 64), rs4 = __shfl(rp, 4, 64);
    int dg0 = rs1 - rs0, dg1 = rs2 - rs1, dg2 = rs3 - rs2, dg3 = rs4 - rs3;
    if (dg0 > 8) dg0 = 8;
    if (dg1 > 8) dg1 = 8;
    if (dg2 > 8) dg2 = 8;
    if (dg3 > 8) dg3 = 8;
    if (nb + 1 >= n) dg1 = 0;
    if (nb + 2 >= n) dg2 = 0;
    if (nb + 3 >= n) dg3 = 0;
    bool ok = (nb + 4 <= n) && (rs0 == nb * 8) && (rs1 == rs0 + 8) &&
              (rs2 == rs1 + 8) && (rs3 == rs2 + 8) && (rs4 == rs3 + 8);
    if (!ok) {  // cold path (never taken for this graph)
        int j = lane >> 3, e = lane & 7;
        int rsj = (j == 0) ? rs0 : (j == 1) ? rs1 : (j == 2) ? rs2 : rs3;
        int dgj = (j == 0) ? dg0 : (j == 1) ? dg1 : (j == 2) ? dg2 : dg3;
        int v = 0;
        if (lane < 32 && e < dgj) v = col_ind[rsj + e];
        ci = v;
    }

    const int ea = (l >> 2) & 7, ha = l & 3;
    const int dsel0 = p ? dg1 : dg0;
    const int dsel1 = p ? dg3 : dg2;
    int sa0 = __shfl(ci, (0 * 2 + p) * 8 + ea, 64);
    int sa1 = __shfl(ci, (1 * 2 + p) * 8 + ea, 64);
    float av0 = (ea < dsel0) ? a_src[(size_t)sa0 * HEADS + ha] : 0.f;
    float av1 = (ea < dsel1) ? a_src[(size_t)sa1 * HEADS + ha] : 0.f;
    float dv0 = (nb + p < n) ? a_dst[(size_t)(nb + p) * HEADS + ha] : 0.f;
    float dv1 = (nb + 2 + p < n) ? a_dst[(size_t)(nb + 2 + p) * HEADS + ha] : 0.f;

#pragma unroll
    for (int q = 0; q < 2; q++) {
        const int node = nb + 2 * q + p;
        const int dsel = q ? dsel1 : dsel0;
        float z = (q ? av1 : av0) + (q ? dv1 : dv0);
        float v = (ea < dsel) ? ((z >= 0.f) ? z : NEG_SLOPE * z) : -1e30f;
        float m = v;
        m = fmaxf(m, __shfl_xor(m, 4, 64));
        m = fmaxf(m, __shfl_xor(m, 8, 64));
        m = fmaxf(m, __shfl_xor(m, 16, 64));
        float ex = (ea < dsel) ? __expf(v - m) : 0.f;
        float ss = ex;
        ss += __shfl_xor(ss, 4, 64);
        ss += __shfl_xor(ss, 8, 64);
        ss += __shfl_xor(ss, 16, 64);
        float al = ex * ((ss > 0.f) ? (1.f / ss) : 0.f);
        if (node < n)
            alpha[(size_t)ha * n * 8 + (size_t)node * 8 + ea] = (f16)al;
    }
}

// ---- sliced aggregation: block (bid&7)==s handles 16-col slice s ----
// XCD round-robin dispatch puts all slice-s blocks on XCD s, whose 4 MB L2
// holds the whole 3.2 MB slice -> gathers are L2 hits after cold fill.
// Wave = 16 nodes; lane = (node nd=lane>>2, col-quad c4=lane&3).
// Edge reduction is IN-REGISTER per lane (no reduce shuffles): loop e=0..7,
// acc += alpha[nd,e] * xp[src[nd,e]][c4*4..+4]. Only broadcast shuffles.
__global__ __launch_bounds__(256) void gat_slice_aggr(
    const f16* __restrict__ xp, const f16* __restrict__ alpha,
    const int* __restrict__ row_ptr, const int* __restrict__ col_ind,
    const float* __restrict__ bias, float* __restrict__ out, int n, int e_total) {
    const int slice = blockIdx.x & 7;
    const int chunk = blockIdx.x >> 3;
    const int lane = threadIdx.x & 63;
    const int nb = chunk * 64 + (threadIdx.x >> 6) * 16;   // wave's base node
    if (nb >= n) return;

    const f16* xps = xp + (size_t)slice * n * 16;
    const f16* alp = alpha + (size_t)(slice >> 1) * n * 8;

    // upfront loads (all independent):
    int rp = 0;
    if (lane < 17) {
        int idx = nb + lane;
        if (idx > n) idx = n;
        rp = row_ptr[idx];
    }
    int ci0 = 0, ci1 = 0;
    {
        long long s0 = (long long)nb * 8 + lane;
        if (s0 < e_total) ci0 = col_ind[s0];
        long long s1 = s0 + 64;
        if (s1 < e_total) ci1 = col_ind[s1];
    }
    int av = 0;   // packed 2 x f16 alpha: flat positions 2*lane, 2*lane+1
    {
        long long fi = (long long)nb * 8 + lane * 2;
        if (fi + 2 <= (long long)n * 8) av = *(const int*)(alp + fi);
    }

    const int nd = lane >> 2, c4 = lane & 3;
    const int node = nb + nd;

    bool ok = __all((lane < 17) ? (rp == (nb + lane) * 8) : 1) && (nb + 16 <= n);

    float a0 = 0.f, a1 = 0.f, a2 = 0.f, a3 = 0.f;
    if (ok) {
#pragma unroll
        for (int e = 0; e < 8; e++) {
            int s0 = __shfl(ci0, (nd & 7) * 8 + e, 64);
            int s1 = __shfl(ci1, (nd & 7) * 8 + e, 64);
            int src = (nd < 8) ? s0 : s1;
            int au = __shfl(av, nd * 4 + (e >> 1), 64);
            unsigned short ab = (e & 1) ? (unsigned short)(((unsigned int)au) >> 16)
                                        : (unsigned short)(au & 0xffff);
            float a = (float)(*(const f16*)&ab);
            f16x4 v = *(const f16x4*)(xps + (size_t)src * 16 + c4 * 4);
            a0 = fmaf(a, (float)v[0], a0);
            a1 = fmaf(a, (float)v[1], a1);
            a2 = fmaf(a, (float)v[2], a2);
            a3 = fmaf(a, (float)v[3], a3);
        }
    } else {  // cold path: generic degrees (never taken for this graph)
        int rs = __shfl(rp, nd, 64);
        int re = __shfl(rp, nd + 1, 64);
        int dg = re - rs;
        if (dg > 8) dg = 8;
        if (node < n) {
            for (int e = 0; e < dg; e++) {
                int src = col_ind[rs + e];
                unsigned short ab = *(const unsigned short*)(alp + (size_t)node * 8 + e);
                float a = (float)(*(const f16*)&ab);
                f16x4 v = *(const f16x4*)(xps + (size_t)src * 16 + c4 * 4);
                a0 = fmaf(a, (float)v[0], a0);
                a1 = fmaf(a, (float)v[1], a1);
                a2 = fmaf(a, (float)v[2], a2);
                a3 = fmaf(a, (float)v[3], a3);
            }
        }
    }

    if (node < n) {
        float4 b4 = *(const float4*)(bias + slice * 16 + c4 * 4);
        f32x4 o;
        o[0] = a0 + b4.x;
        o[1] = a1 + b4.y;
        o[2] = a2 + b4.z;
        o[3] = a3 + b4.w;
        __builtin_nontemporal_store(o, (f32x4*)(out + (size_t)node * 128 + slice * 16 + c4 * 4));
    }
}

extern "C" void kernel_launch(void* const* d_in, const int* in_sizes, int n_in,
                              void* d_out, int out_size, void* d_ws, size_t ws_size,
                              hipStream_t stream) {
    const float* x = (const float*)d_in[0];
    const int* row_ptr = (const int*)d_in[1];
    const int* col_ind = (const int*)d_in[2];
    // d_in[3] = max_num_neighbors (row_ptr is authoritative)
    const float* lin_w = (const float*)d_in[4];
    const float* att = (const float*)d_in[5];
    const float* bias = (const float*)d_in[6];
    float* out = (float*)d_out;
    const int n = in_sizes[0] / 128;
    const int e_total = in_sizes[2];

    // ws layout
    f16* xp = (f16*)d_ws;                                   // [8][n][16] f16 = n*256 B
    float* a_src = (float*)((char*)d_ws + (size_t)n * 256); // n*4 f32
    float* a_dst = a_src + (size_t)n * HEADS;               // n*4 f32
    f16* alpha = (f16*)(a_dst + (size_t)n * HEADS);         // [4][n*8] f16
    f16* wt = alpha + (size_t)n * 32 + 128;                 // 128*128 f16 (+pad)

    hipLaunchKernelGGL(wt_kernel, dim3(8), dim3(256), 0, stream, lin_w, wt);
    hipLaunchKernelGGL(gat_proj_mfma, dim3((n + MB - 1) / MB), dim3(256), 0, stream,
                       x, wt, att, xp, a_src, a_dst, n);
    hipLaunchKernelGGL(gat_alpha_kernel, dim3((n + 15) / 16), dim3(256), 0, stream,
                       a_src, a_dst, row_ptr, col_ind, alpha, n, e_total);
    hipLaunchKernelGGL(gat_slice_aggr, dim3(8 * ((n + 63) / 64)), dim3(256), 0, stream,
                       xp, alpha, row_ptr, col_ind, bias, out, n, e_total);
}

// Round 9
// 75.351 us; speedup vs baseline: 1.4738x; 1.0328x over previous
//
#include <hip/hip_runtime.h>
#include <stdint.h>

#define HEADS 4
#define NEG_SLOPE 0.2f
#define MB 64      // rows per block in projection kernel

typedef _Float16 f16;
typedef f16 f16x8 __attribute__((ext_vector_type(8)));
typedef f16 f16x4 __attribute__((ext_vector_type(4)));
typedef float f32x4 __attribute__((ext_vector_type(4)));
typedef unsigned int u32x4 __attribute__((ext_vector_type(4)));

// swizzled LDS byte offset for a [rows][128] f16 tile (256 B rows):
// XOR row bits into the 16B-slot bits to kill the 16-way bank conflict
#define SWZ(row, kb) (((row) << 8) + ((kb) ^ (((row) & 7) << 4)))

// ---- pre-kernel: w (f32 [K=128][N=128]) -> wt (f16 [N=128][K=128]) ----
__global__ __launch_bounds__(256) void wt_kernel(const float* __restrict__ w,
                                                 f16* __restrict__ wt) {
    __shared__ f16 tl[16][136];  // +8 pad
    const int b = blockIdx.x, t = threadIdx.x;
    for (int i = t; i < 2048; i += 256) {   // 128 k-rows x 16 cols of this slice
        int k = i >> 4, nl = i & 15;
        tl[nl][k] = (f16)w[k * 128 + b * 16 + nl];
    }
    __syncthreads();
    {
        int nl = t >> 4, kc = t & 15;       // 16 rows x 16 chunks = 256 threads
        f16x8 v = *(const f16x8*)&tl[nl][kc * 8];
        *(f16x8*)(wt + (b * 16 + nl) * 128 + kc * 8) = v;
    }
}

// ---- projection: xp = f16(x) @ f16(w) via MFMA + a_src/a_dst logit dots ----
// xp is written in 4-slice layout: [4 slices of 32 cols][node][32] f16 (64 B
// rows, one full cache line per edge-gather). Slice s == head s.
__global__ __launch_bounds__(256) void gat_proj_mfma(
    const float* __restrict__ x, const f16* __restrict__ wt,
    const float* __restrict__ att, f16* __restrict__ xp,
    float* __restrict__ a_src, float* __restrict__ a_dst, int n) {
    __shared__ unsigned char lds[32768];
    __shared__ float att_l[256];
    const int t = threadIdx.x;
    const int node0 = blockIdx.x * MB;
    const int lane = t & 63;
    const int wv = t >> 6;

    att_l[t] = att[t];

    // A-frags: row = node0 + wv*16 + (lane&15); kt-frag cols kt*32+(lane>>4)*8..+8
    const int arow = node0 + wv * 16 + (lane & 15);
    const bool rowok = arow < n;
    const float* xr = x + (size_t)arow * 128 + (lane >> 4) * 8;
    f16x8 afr[4];
#pragma unroll
    for (int kt = 0; kt < 4; kt++) {
        float4 a = make_float4(0.f, 0.f, 0.f, 0.f), b = a;
        if (rowok) {
            a = *(const float4*)(xr + kt * 32);
            b = *(const float4*)(xr + kt * 32 + 4);
        }
        f16x8 hv;
        hv[0] = (f16)a.x; hv[1] = (f16)a.y; hv[2] = (f16)a.z; hv[3] = (f16)a.w;
        hv[4] = (f16)b.x; hv[5] = (f16)b.y; hv[6] = (f16)b.z; hv[7] = (f16)b.w;
        afr[kt] = hv;
    }

    // stage wt (f16, [N][K]) into swizzled LDS
    for (int i = t; i < 2048; i += 256) {
        int row = i >> 4, kc = i & 15;
        uint4 v = *(const uint4*)(wt + row * 128 + kc * 8);
        *(uint4*)(lds + SWZ(row, kc * 16)) = v;
    }
    __syncthreads();

    // MFMA: wave wv owns rows wv*16..+15 (1 M-frag), all 128 cols
    f32x4 acc[8];
#pragma unroll
    for (int nf = 0; nf < 8; nf++) acc[nf] = (f32x4){0.f, 0.f, 0.f, 0.f};

#pragma unroll
    for (int kt = 0; kt < 4; kt++) {
        const int kb = kt * 64 + (lane >> 4) * 16;
#pragma unroll
        for (int nf = 0; nf < 8; nf++) {
            f16x8 bfr = *(const f16x8*)(lds + SWZ(nf * 16 + (lane & 15), kb));
            acc[nf] = __builtin_amdgcn_mfma_f32_16x16x32_f16(afr[kt], bfr, acc[nf], 0, 0, 0);
        }
    }

    // repack accumulators (f16) into the (now-free) wt LDS region
    __syncthreads();  // all wt reads done
#pragma unroll
    for (int r = 0; r < 4; r++) {
        int row = wv * 16 + (lane >> 4) * 4 + r;
#pragma unroll
        for (int nf = 0; nf < 8; nf++) {
            int col = nf * 16 + (lane & 15);
            *(f16*)(lds + SWZ(row, col * 2)) = (f16)acc[nf][r];
        }
    }
    __syncthreads();

    // a_src[n,h] = sum_c xp[n,h*32+c]*att[h*32+c]; a_dst with att[128+..]
    {
        int row = t >> 2, h = t & 3;        // 64 rows x 4 heads = 256 threads
        int grow = node0 + row;
        if (grow < n) {
            float s = 0.f, d = 0.f;
#pragma unroll
            for (int cc = 0; cc < 4; cc++) {
                f16x8 v = *(const f16x8*)(lds + SWZ(row, h * 64 + cc * 16));
#pragma unroll
                for (int j = 0; j < 8; j++) {
                    float xv = (float)v[j];
                    int c = cc * 8 + j;
                    s = fmaf(xv, att_l[h * 32 + c], s);
                    d = fmaf(xv, att_l[128 + h * 32 + c], d);
                }
            }
            a_src[(size_t)grow * HEADS + h] = s;
            a_dst[(size_t)grow * HEADS + h] = d;
        }
    }
    // write xp tile out in 4-slice layout (16B stores, NORMAL caching)
    for (int i = t; i < 1024; i += 256) {
        int row = i >> 4, kc = i & 15;
        int grow = node0 + row;
        if (grow < n) {
            u32x4 v = *(const u32x4*)(lds + SWZ(row, kc * 16));
            int slice = kc >> 2;
            *(u32x4*)(xp + ((size_t)slice * n + grow) * 32 + (kc & 3) * 8) = v;
        }
    }
}

// ---- alpha kernel: per-edge softmax weights into per-head planes ----
// alpha[h][node*8+e] (f16), 0 for invalid edge slots. 8 nodes per wave;
// lane = (node j=lane>>3, edge e=lane&7). One 16 B a_src gather per edge
// covers all 4 heads; softmax via xor-1/2/4 within each 8-lane edge group.
__global__ __launch_bounds__(256) void gat_alpha_kernel(
    const float* __restrict__ a_src, const float* __restrict__ a_dst,
    const int* __restrict__ row_ptr, const int* __restrict__ col_ind,
    f16* __restrict__ alpha, int n, int e_total) {
    const int lane = threadIdx.x & 63;
    const int nb = (blockIdx.x * 4 + (threadIdx.x >> 6)) * 8;
    if (nb >= n) return;
    const int j = lane >> 3, e = lane & 7;
    const int node = nb + j;

    int rp = 0;
    if (lane < 9) {
        int idx = nb + lane;
        if (idx > n) idx = n;
        rp = row_ptr[idx];
    }
    bool ok = __all((lane < 9) ? (rp == (nb + lane) * 8) : 1) && (nb + 8 <= n);

    int ci = 0;
    bool valid;
    if (ok) {
        ci = col_ind[nb * 8 + lane];
        valid = true;
    } else {  // cold path (never taken for this graph)
        int rs = __shfl(rp, j, 64), re = __shfl(rp, j + 1, 64);
        int dg = re - rs;
        if (dg > 8) dg = 8;
        valid = (node < n) && (e < dg);
        if (valid) ci = col_ind[rs + e];
    }

    f32x4 asv = (f32x4){0.f, 0.f, 0.f, 0.f};
    if (valid) asv = *(const f32x4*)(a_src + (size_t)ci * HEADS);
    f32x4 adv = (f32x4){0.f, 0.f, 0.f, 0.f};
    if (node < n) adv = *(const f32x4*)(a_dst + (size_t)node * HEADS);

#pragma unroll
    for (int h = 0; h < HEADS; h++) {
        float z = asv[h] + adv[h];
        z = (z >= 0.f) ? z : NEG_SLOPE * z;
        float v = valid ? z : -1e30f;
        float m = v;
        m = fmaxf(m, __shfl_xor(m, 1, 64));
        m = fmaxf(m, __shfl_xor(m, 2, 64));
        m = fmaxf(m, __shfl_xor(m, 4, 64));
        float ex = valid ? __expf(v - m) : 0.f;
        float ss = ex;
        ss += __shfl_xor(ss, 1, 64);
        ss += __shfl_xor(ss, 2, 64);
        ss += __shfl_xor(ss, 4, 64);
        float al = ex * ((ss > 0.f) ? (1.f / ss) : 0.f);
        if (node < n)
            alpha[(size_t)h * n * 8 + (size_t)node * 8 + e] = (f16)al;
    }
}

// ---- sliced aggregation: block (bid&3)==s handles 32-col slice s ----
// Round-robin dispatch puts slice-s blocks on XCDs {s, s+4}; each XCD's 4 MB
// L2 caches most of its 6.4 MB slice. One gather = one full 64 B line.
// Wave = 8 nodes; lane = (node nd=lane>>3, col-oct c=lane&7). Edge reduction
// in-register per lane (broadcast shuffles only, no reduce shuffles).
__global__ __launch_bounds__(256) void gat_slice_aggr(
    const f16* __restrict__ xp, const f16* __restrict__ alpha,
    const int* __restrict__ row_ptr, const int* __restrict__ col_ind,
    const float* __restrict__ bias, float* __restrict__ out, int n, int e_total) {
    const int slice = blockIdx.x & 3;
    const int chunk = blockIdx.x >> 2;
    const int lane = threadIdx.x & 63;
    const int nb = chunk * 32 + (threadIdx.x >> 6) * 8;   // wave's base node
    if (nb >= n) return;

    const f16* xps = xp + (size_t)slice * n * 32;
    const f16* alp = alpha + (size_t)slice * n * 8;       // slice == head
    const int nd = lane >> 3, c = lane & 7;
    const int node = nb + nd;

    // upfront loads (all independent)
    int rp = 0;
    if (lane < 9) {
        int idx = nb + lane;
        if (idx > n) idx = n;
        rp = row_ptr[idx];
    }
    int ci = 0;
    {
        long long si = (long long)nb * 8 + lane;
        if (si < e_total) ci = col_ind[si];
    }
    int av = 0;   // packed 2 x f16 alpha: flat edge slots 2*lane, 2*lane+1
    if (lane < 32) {
        long long fi = (long long)nb * 8 + lane * 2;
        if (fi + 2 <= (long long)n * 8) av = *(const int*)(alp + fi);
    }
    float4 b4 = *(const float4*)(bias + slice * 32 + c * 4);

    bool ok = __all((lane < 9) ? (rp == (nb + lane) * 8) : 1) && (nb + 8 <= n);

    float a0 = 0.f, a1 = 0.f, a2 = 0.f, a3 = 0.f;
    if (ok) {
#pragma unroll
        for (int e = 0; e < 8; e++) {
            int src = __shfl(ci, nd * 8 + e, 64);
            int au = __shfl(av, (nd * 8 + e) >> 1, 64);
            unsigned short ab = (e & 1) ? (unsigned short)(((unsigned int)au) >> 16)
                                        : (unsigned short)(au & 0xffff);
            float a = (float)(*(const f16*)&ab);
            f16x4 v = *(const f16x4*)(xps + (size_t)src * 32 + c * 4);
            a0 = fmaf(a, (float)v[0], a0);
            a1 = fmaf(a, (float)v[1], a1);
            a2 = fmaf(a, (float)v[2], a2);
            a3 = fmaf(a, (float)v[3], a3);
        }
    } else {  // cold path: generic degrees (never taken for this graph)
        int rs = __shfl(rp, nd, 64);
        int re = __shfl(rp, nd + 1, 64);
        int dg = re - rs;
        if (dg > 8) dg = 8;
        if (node < n) {
            for (int e = 0; e < dg; e++) {
                int src = col_ind[rs + e];
                unsigned short ab = *(const unsigned short*)(alp + (size_t)node * 8 + e);
                float a = (float)(*(const f16*)&ab);
                f16x4 v = *(const f16x4*)(xps + (size_t)src * 32 + c * 4);
                a0 = fmaf(a, (float)v[0], a0);
                a1 = fmaf(a, (float)v[1], a1);
                a2 = fmaf(a, (float)v[2], a2);
                a3 = fmaf(a, (float)v[3], a3);
            }
        }
    }

    if (node < n) {
        f32x4 o;
        o[0] = a0 + b4.x;
        o[1] = a1 + b4.y;
        o[2] = a2 + b4.z;
        o[3] = a3 + b4.w;
        __builtin_nontemporal_store(o, (f32x4*)(out + (size_t)node * 128 + slice * 32 + c * 4));
    }
}

extern "C" void kernel_launch(void* const* d_in, const int* in_sizes, int n_in,
                              void* d_out, int out_size, void* d_ws, size_t ws_size,
                              hipStream_t stream) {
    const float* x = (const float*)d_in[0];
    const int* row_ptr = (const int*)d_in[1];
    const int* col_ind = (const int*)d_in[2];
    // d_in[3] = max_num_neighbors (row_ptr is authoritative)
    const float* lin_w = (const float*)d_in[4];
    const float* att = (const float*)d_in[5];
    const float* bias = (const float*)d_in[6];
    float* out = (float*)d_out;
    const int n = in_sizes[0] / 128;
    const int e_total = in_sizes[2];

    // ws layout
    f16* xp = (f16*)d_ws;                                   // [4][n][32] f16 = n*256 B
    float* a_src = (float*)((char*)d_ws + (size_t)n * 256); // n*4 f32
    float* a_dst = a_src + (size_t)n * HEADS;               // n*4 f32
    f16* alpha = (f16*)(a_dst + (size_t)n * HEADS);         // [4][n*8] f16
    f16* wt = alpha + (size_t)n * 32 + 128;                 // 128*128 f16 (+pad)

    hipLaunchKernelGGL(wt_kernel, dim3(8), dim3(256), 0, stream, lin_w, wt);
    hipLaunchKernelGGL(gat_proj_mfma, dim3((n + MB - 1) / MB), dim3(256), 0, stream,
                       x, wt, att, xp, a_src, a_dst, n);
    hipLaunchKernelGGL(gat_alpha_kernel, dim3((n + 31) / 32), dim3(256), 0, stream,
                       a_src, a_dst, row_ptr, col_ind, alpha, n, e_total);
    hipLaunchKernelGGL(gat_slice_aggr, dim3(4 * ((n + 31) / 32)), dim3(256), 0, stream,
                       xp, alpha, row_ptr, col_ind, bias, out, n, e_total);
}